// Round 5
// baseline (103.741 us; speedup 1.0000x reference)
//
#include <hip/hip_runtime.h>
#include <stdint.h>

// VarifoldKernel: out[b] = sum_{n,m} w1[b,n]*w2[b,m]*exp(-2*||p1-p2||^2)*exp(-f1.f2/2)
// Log-space: term = 2^( dot(U1[n],U2[m]) + la1[n] + la2[m] ),
//   U1 = [2*pos1, feat1] fp16, U2 = [2*L*pos2, -0.5*L*feat2] fp16, L = log2(e)
//   la = log2(w) - 2*L*|pos|^2
// K = 67 padded to 96. fp16 MFMA 16x16x32, fp32 accumulate.
// R5: occupancy experiment — 32 waves/CU (8 blocks/CU, <=64 VGPR/wave).
//     Wave owns 32 cols (bf[3][2] = 24 VGPR persistent), no prefetch dbuf
//     (TLP hides per-tile L2 latency at 8 waves/SIMD), no LDS/barriers in
//     the main kernel. Evidence: varifold time scaled ~1/(waves/CU) from
//     R1(8w: 59us) to R2/R3(16w: ~31us) regardless of structure.

typedef _Float16 f16;
typedef _Float16 v8h __attribute__((ext_vector_type(8)));
typedef _Float16 h4  __attribute__((ext_vector_type(4)));
typedef float    v4f __attribute__((ext_vector_type(4)));

#define L2E 1.4426950408889634f
#define BN 4096
#define KP 96    // padded K (halfs); row = 192 B

// ---------------- prep: fp32 -> fp16 U matrices + log-space row terms ----------------
__global__ __launch_bounds__(256) void prep_kernel(
    const float* __restrict__ pos1, const float* __restrict__ feat1, const float* __restrict__ w1,
    const float* __restrict__ pos2, const float* __restrict__ feat2, const float* __restrict__ w2,
    f16* __restrict__ U1, f16* __restrict__ U2,
    float* __restrict__ la1, float* __restrict__ la2)
{
    int tid  = threadIdx.x;
    int ridx = blockIdx.x * 16 + (tid >> 4);   // 0..32767
    int c    = tid & 15;
    int side = ridx >> 14;                     // 0: side1, 1: side2
    int idx  = ridx & 16383;                   // b*4096 + row

    const float* feat = side ? feat2 : feat1;
    f16* U   = side ? U2 : U1;
    float fs = side ? -0.5f * L2E : 1.0f;

    float4 v = ((const float4*)feat)[idx * 16 + c];
    *(h4*)(U + (long)idx * KP + 4 + c * 4) =
        h4{(f16)(v.x * fs), (f16)(v.y * fs), (f16)(v.z * fs), (f16)(v.w * fs)};

    if (c == 0) {
        const float* pos = side ? pos2 : pos1;
        const float* w   = side ? w2   : w1;
        float* la = side ? la2 : la1;
        float ps  = side ? 2.0f * L2E : 2.0f;
        float p0 = pos[idx*3+0], p1 = pos[idx*3+1], p2 = pos[idx*3+2];
        la[idx] = __builtin_amdgcn_logf(w[idx]) - 2.0f * L2E * (p0*p0 + p1*p1 + p2*p2);
        *(h4*)(U + (long)idx * KP) = h4{(f16)(p0*ps), (f16)(p1*ps), (f16)(p2*ps), (f16)0.0f};
    } else if (c <= 7) {
        *(h4*)(U + (long)idx * KP + 68 + (c - 1) * 4) =
            h4{(f16)0.0f, (f16)0.0f, (f16)0.0f, (f16)0.0f};
    }
}

// ---------------- main: 32 waves/CU, slim-register, barrier-free --------------------
// Block = 4 waves, no shared state. Wave w owns cols [stripe*128 + w*32, +32)
// against the block's 256-row chunk. B frags (24 VGPR) persist; A frags loaded
// per 16-row tile (no dbuf — TLP at 8 waves/SIMD hides L2 latency).
__global__ __launch_bounds__(256, 8) void varifold_kernel(
    const f16* __restrict__ U1, const f16* __restrict__ U2,
    const float* __restrict__ la1, const float* __restrict__ la2,
    float* __restrict__ pw)
{
    int tid = threadIdx.x, wave = tid >> 6, lane = tid & 63;
    int stripe = blockIdx.x, nchunk = blockIdx.y, b = blockIdx.z;
    int l15 = lane & 15, quad = lane >> 4;

    long colr = (long)b*BN + stripe*128 + wave*32;   // this wave's first col row-index
    long row0 = (long)b*BN + nchunk*256;             // this block's first row

    // --- persistent B fragments + la2 (2 j-tiles x 3 ksteps = 24 VGPRs) ---
    v8h bf[3][2];
    float la2v[2];
    #pragma unroll
    for (int j = 0; j < 2; ++j) {
        const f16* r = U2 + (colr + j*16 + l15) * KP + quad*8;
        bf[0][j] = *(const v8h*)(r);
        bf[1][j] = *(const v8h*)(r + 32);
        bf[2][j] = *(const v8h*)(r + 64);
        la2v[j]  = la2[colr + j*16 + l15];
    }

    const f16* Ab = U1 + (row0 + l15) * KP + quad*8;  // A frag base (+16 rows/tile)

    float psum = 0.f;
    #pragma unroll 1
    for (int t = 0; t < 16; ++t) {
        const f16* Ar = Ab + t * 16 * KP;
        v8h a0 = *(const v8h*)(Ar);
        v8h a1 = *(const v8h*)(Ar + 32);
        v8h a2 = *(const v8h*)(Ar + 64);

        v4f acc0 = v4f{0.f, 0.f, 0.f, 0.f};
        v4f acc1 = v4f{0.f, 0.f, 0.f, 0.f};
        acc0 = __builtin_amdgcn_mfma_f32_16x16x32_f16(a0, bf[0][0], acc0, 0, 0, 0);
        acc1 = __builtin_amdgcn_mfma_f32_16x16x32_f16(a0, bf[0][1], acc1, 0, 0, 0);
        acc0 = __builtin_amdgcn_mfma_f32_16x16x32_f16(a1, bf[1][0], acc0, 0, 0, 0);
        acc1 = __builtin_amdgcn_mfma_f32_16x16x32_f16(a1, bf[1][1], acc1, 0, 0, 0);
        acc0 = __builtin_amdgcn_mfma_f32_16x16x32_f16(a2, bf[2][0], acc0, 0, 0, 0);
        acc1 = __builtin_amdgcn_mfma_f32_16x16x32_f16(a2, bf[2][1], acc1, 0, 0, 0);

        // epilogue: C/D layout col=lane&15, row=quad*4+reg
        float4 l1 = *(const float4*)(la1 + row0 + t*16 + quad*4);
        psum += __builtin_amdgcn_exp2f(acc0[0] + l1.x + la2v[0]);
        psum += __builtin_amdgcn_exp2f(acc0[1] + l1.y + la2v[0]);
        psum += __builtin_amdgcn_exp2f(acc0[2] + l1.z + la2v[0]);
        psum += __builtin_amdgcn_exp2f(acc0[3] + l1.w + la2v[0]);
        psum += __builtin_amdgcn_exp2f(acc1[0] + l1.x + la2v[1]);
        psum += __builtin_amdgcn_exp2f(acc1[1] + l1.y + la2v[1]);
        psum += __builtin_amdgcn_exp2f(acc1[2] + l1.z + la2v[1]);
        psum += __builtin_amdgcn_exp2f(acc1[3] + l1.w + la2v[1]);
    }

    // --- wave reduce -> one plain store per wave (no atomics, no LDS) ---
    #pragma unroll
    for (int off = 32; off > 0; off >>= 1) psum += __shfl_down(psum, off);
    if (lane == 0)
        pw[(((long)b*16 + nchunk)*32 + stripe)*4 + wave] = psum;
}

// ---------------- final: reduce 2048 partials per batch -> out[b] -------------------
__global__ __launch_bounds__(256) void reduce_kernel(
    const float* __restrict__ pw, float* __restrict__ out)
{
    __shared__ float sred[4];
    int b = blockIdx.x, tid = threadIdx.x;
    const float* p = pw + (long)b * 2048;
    float v = 0.f;
    #pragma unroll
    for (int k = 0; k < 8; ++k) v += p[tid + k * 256];
    #pragma unroll
    for (int off = 32; off > 0; off >>= 1) v += __shfl_down(v, off);
    if ((tid & 63) == 0) sred[tid >> 6] = v;
    __syncthreads();
    if (tid == 0) out[b] = sred[0] + sred[1] + sred[2] + sred[3];
}

extern "C" void kernel_launch(void* const* d_in, const int* in_sizes, int n_in,
                              void* d_out, int out_size, void* d_ws, size_t ws_size,
                              hipStream_t stream) {
    const float* pos1  = (const float*)d_in[0];
    const float* feat1 = (const float*)d_in[1];
    const float* w1    = (const float*)d_in[2];
    const float* pos2  = (const float*)d_in[3];
    const float* feat2 = (const float*)d_in[4];
    const float* w2    = (const float*)d_in[5];
    float* out = (float*)d_out;

    // workspace layout (6,455,296 B)
    char* ws = (char*)d_ws;
    f16*   U1  = (f16*)(ws);                          // 3,145,728
    f16*   U2  = (f16*)(ws + 3145728);                // 3,145,728
    float* la1 = (float*)(ws + 6291456);              // 65,536
    float* la2 = (float*)(ws + 6291456 + 65536);      // 65,536
    float* pw  = (float*)(ws + 6291456 + 131072);     // 8192*4 = 32,768

    prep_kernel<<<2048, 256, 0, stream>>>(pos1, feat1, w1, pos2, feat2, w2, U1, U2, la1, la2);
    dim3 grid(32, 16, 4);  // (stripe, nchunk, b) — stripe fastest for A-row L2 locality
    varifold_kernel<<<grid, 256, 0, stream>>>(U1, U2, la1, la2, pw);
    reduce_kernel<<<4, 256, 0, stream>>>(pw, out);
}

// Round 6
// 88.450 us; speedup vs baseline: 1.1729x; 1.1729x over previous
//
#include <hip/hip_runtime.h>
#include <stdint.h>

// VarifoldKernel: out[b] = sum_{n,m} w1[b,n]*w2[b,m]*exp(-2*||p1-p2||^2)*exp(-f1.f2/2)
// Log-space: term = 2^( dot(A1[n], A2[m]) ) where the K=96-padded rows carry
//   A1 = [2*pos1, 0, feat1,            la1_hi, la1_lo, 1, 1, 0...]   (fp16)
//   A2 = [2*L*pos2, 0, -0.5*L*feat2,   1, 1, la2_hi, la2_lo, 0...]   (fp16)
//   la = clamp(log2(w) - 2*L*|pos|^2, >= -1000), hi/lo fp16 split, L = log2(e)
// => the MFMA accumulator exits with dot + la1 + la2 already summed; epilogue
//    is just psum += exp2(acc). R6 = R3 core (register-persistent B stripe,
//    barrier-free, 1-tile A prefetch, 4 blocks/CU) + this epilogue diet.

typedef _Float16 f16;
typedef _Float16 v8h __attribute__((ext_vector_type(8)));
typedef _Float16 h4  __attribute__((ext_vector_type(4)));
typedef float    v4f __attribute__((ext_vector_type(4)));

#define L2E 1.4426950408889634f
#define BN 4096
#define KP 96    // padded K (halfs); row = 192 B

// ---------------- prep: fp32 -> fp16 U matrices (log terms folded into K-pad) -------
__global__ __launch_bounds__(256) void prep_kernel(
    const float* __restrict__ pos1, const float* __restrict__ feat1, const float* __restrict__ w1,
    const float* __restrict__ pos2, const float* __restrict__ feat2, const float* __restrict__ w2,
    f16* __restrict__ U1, f16* __restrict__ U2)
{
    int tid  = threadIdx.x;
    int ridx = blockIdx.x * 16 + (tid >> 4);   // 0..32767
    int c    = tid & 15;
    int side = ridx >> 14;                     // 0: side1, 1: side2
    int idx  = ridx & 16383;                   // b*4096 + row

    const float* feat = side ? feat2 : feat1;
    f16* U   = side ? U2 : U1;
    float fs = side ? -0.5f * L2E : 1.0f;

    // feat -> halfs 4..67 (c-th float4 -> h4 at 4+4c), coalesced
    float4 v = ((const float4*)feat)[idx * 16 + c];
    *(h4*)(U + (long)idx * KP + 4 + c * 4) =
        h4{(f16)(v.x * fs), (f16)(v.y * fs), (f16)(v.z * fs), (f16)(v.w * fs)};

    if (c == 0) {
        const float* pos = side ? pos2 : pos1;
        const float* w   = side ? w2   : w1;
        float ps  = side ? 2.0f * L2E : 2.0f;
        float p0 = pos[idx*3+0], p1 = pos[idx*3+1], p2 = pos[idx*3+2];
        // log-space row term, clamped so w==0 can't yield -inf (then lo would be NaN)
        float la = __builtin_amdgcn_logf(w[idx]) - 2.0f * L2E * (p0*p0 + p1*p1 + p2*p2);
        la = fmaxf(la, -1000.0f);
        f16   hi = (f16)la;
        f16   lo = (f16)(la - (float)hi);
        *(h4*)(U + (long)idx * KP) = h4{(f16)(p0*ps), (f16)(p1*ps), (f16)(p2*ps), (f16)0.0f};
        // k68..71: A-side carries {la1_hi, la1_lo, 1, 1}; B-side {1, 1, la2_hi, la2_lo}
        *(h4*)(U + (long)idx * KP + 68) =
            side ? h4{(f16)1.0f, (f16)1.0f, hi, lo}
                 : h4{hi, lo, (f16)1.0f, (f16)1.0f};
    } else if (c <= 6) {
        // k72..95 zero (6 x h4)
        *(h4*)(U + (long)idx * KP + 72 + (c - 1) * 4) =
            h4{(f16)0.0f, (f16)0.0f, (f16)0.0f, (f16)0.0f};
    }
}

// ---------------- main: barrier-free, register-persistent B stripe (R3 core) --------
// Block = 4 waves. Wave w owns cols [stripe*256 + w*64, +64) for a 256-row chunk.
// B frags persist in registers; A frags loaded per 16-row tile with 1-tile prefetch.
// Epilogue: psum += exp2(acc) — la terms already inside the accumulator.
__global__ __launch_bounds__(256, 4) void varifold_kernel(
    const f16* __restrict__ U1, const f16* __restrict__ U2,
    float* __restrict__ pw)
{
    int tid = threadIdx.x, wave = tid >> 6, lane = tid & 63;
    int stripe = blockIdx.x, nchunk = blockIdx.y, b = blockIdx.z;
    int l15 = lane & 15, quad = lane >> 4;

    long colr = (long)b*BN + stripe*256 + wave*64;   // this wave's first col row-index
    long row0 = (long)b*BN + nchunk*256;             // this block's first row

    // --- persistent B fragments (registers for whole kernel) ---
    v8h bf[3][4];
    #pragma unroll
    for (int j = 0; j < 4; ++j) {
        const f16* r = U2 + (colr + j*16 + l15) * KP + quad*8;
        bf[0][j] = *(const v8h*)(r);
        bf[1][j] = *(const v8h*)(r + 32);
        bf[2][j] = *(const v8h*)(r + 64);
    }

    const f16* Ab = U1 + (row0 + l15) * KP + quad*8;  // A frag base (+16 rows/tile)
    v8h afc[3], afn[3];
    afc[0] = *(const v8h*)(Ab);
    afc[1] = *(const v8h*)(Ab + 32);
    afc[2] = *(const v8h*)(Ab + 64);

    float psum = 0.f;
    #pragma unroll 2
    for (int t = 0; t < 16; ++t) {
        // prefetch next tile's A fragments (clamped; last iter re-loads self)
        const f16* An = Ab + (t < 15 ? (t+1) : t) * 16 * KP;
        afn[0] = *(const v8h*)(An);
        afn[1] = *(const v8h*)(An + 32);
        afn[2] = *(const v8h*)(An + 64);

        v4f acc[4];
        #pragma unroll
        for (int j = 0; j < 4; ++j) acc[j] = v4f{0.f, 0.f, 0.f, 0.f};
        #pragma unroll
        for (int k = 0; k < 3; ++k)
            #pragma unroll
            for (int j = 0; j < 4; ++j)
                acc[j] = __builtin_amdgcn_mfma_f32_16x16x32_f16(afc[k], bf[k][j], acc[j], 0, 0, 0);

        // epilogue: accumulator already holds dot + la1 + la2
        #pragma unroll
        for (int j = 0; j < 4; ++j) {
            psum += __builtin_amdgcn_exp2f(acc[j][0]);
            psum += __builtin_amdgcn_exp2f(acc[j][1]);
            psum += __builtin_amdgcn_exp2f(acc[j][2]);
            psum += __builtin_amdgcn_exp2f(acc[j][3]);
        }

        afc[0] = afn[0]; afc[1] = afn[1]; afc[2] = afn[2];
    }

    // --- wave reduce -> one plain store per wave (no atomics, no LDS) ---
    #pragma unroll
    for (int off = 32; off > 0; off >>= 1) psum += __shfl_down(psum, off);
    if (lane == 0)
        pw[(((long)b*16 + nchunk)*16 + stripe)*4 + wave] = psum;
}

// ---------------- final: reduce 1024 partials per batch -> out[b] -------------------
__global__ __launch_bounds__(256) void reduce_kernel(
    const float* __restrict__ pw, float* __restrict__ out)
{
    __shared__ float sred[4];
    int b = blockIdx.x, tid = threadIdx.x;
    const float* p = pw + (long)b * 1024;
    float v = p[tid] + p[tid + 256] + p[tid + 512] + p[tid + 768];
    #pragma unroll
    for (int off = 32; off > 0; off >>= 1) v += __shfl_down(v, off);
    if ((tid & 63) == 0) sred[tid >> 6] = v;
    __syncthreads();
    if (tid == 0) out[b] = sred[0] + sred[1] + sred[2] + sred[3];
}

extern "C" void kernel_launch(void* const* d_in, const int* in_sizes, int n_in,
                              void* d_out, int out_size, void* d_ws, size_t ws_size,
                              hipStream_t stream) {
    const float* pos1  = (const float*)d_in[0];
    const float* feat1 = (const float*)d_in[1];
    const float* w1    = (const float*)d_in[2];
    const float* pos2  = (const float*)d_in[3];
    const float* feat2 = (const float*)d_in[4];
    const float* w2    = (const float*)d_in[5];
    float* out = (float*)d_out;

    // workspace layout (6,307,840 B)
    char* ws = (char*)d_ws;
    f16*   U1  = (f16*)(ws);                          // 3,145,728
    f16*   U2  = (f16*)(ws + 3145728);                // 3,145,728
    float* pw  = (float*)(ws + 6291456);              // 4096*4 = 16,384

    prep_kernel<<<2048, 256, 0, stream>>>(pos1, feat1, w1, pos2, feat2, w2, U1, U2);
    dim3 grid(16, 16, 4);  // (stripe, nchunk, b) — stripe fastest for A-row L2 locality
    varifold_kernel<<<grid, 256, 0, stream>>>(U1, U2, pw);
    reduce_kernel<<<4, 256, 0, stream>>>(pw, out);
}